// Round 11
// baseline (191.086 us; speedup 1.0000x reference)
//
#include <hip/hip_runtime.h>
#include <hip/hip_bf16.h>

#define N_NODES 10000
#define KP      10240   // K padded; xwt pad slabs are ZERO
#define F       128
#define SPLITS  8
#define KSPLIT  1280    // KP / SPLITS
#define BK      128
#define TPS     10      // KSPLIT / BK
#define BM      128
#define MBLK    79      // ceil(10000/128)
#define PROWS   10112   // MBLK*128

typedef float  f32x4  __attribute__((ext_vector_type(4)));
typedef short  bf16x8 __attribute__((ext_vector_type(8)));
typedef short  s16x8  __attribute__((ext_vector_type(8)));

static __device__ __forceinline__ unsigned short f2bf(float f) {
    unsigned u = __builtin_bit_cast(unsigned, f);
    u += 0x7FFFu + ((u >> 16) & 1u);
    return (unsigned short)(u >> 16);
}

static __device__ __forceinline__ bf16x8 pack8(f32x4 lo, f32x4 hi) {
    bf16x8 r;
    r[0] = (short)f2bf(lo[0]); r[1] = (short)f2bf(lo[1]);
    r[2] = (short)f2bf(lo[2]); r[3] = (short)f2bf(lo[3]);
    r[4] = (short)f2bf(hi[0]); r[5] = (short)f2bf(hi[1]);
    r[6] = (short)f2bf(hi[2]); r[7] = (short)f2bf(hi[3]);
    return r;
}

// ---------------------------------------------------------------------------
// Kernel 1: xwt = (X @ W1)^T bf16 in MFMA-native tiles (validated R10 layout):
//   [kc(320)][ct(8)][c(16)][k(32)] ; each 16c x 32k subtile = 1KB contiguous.
// grid 640 x 256; pad k (nodes >= 10000) -> 0.
// ---------------------------------------------------------------------------
__global__ __launch_bounds__(256) void k_xw(const float* __restrict__ x,
                                            const float* __restrict__ W1,
                                            unsigned short* __restrict__ xwt) {
    __shared__ float xs[16][128];
    __shared__ unsigned short ts[16][136];
    const int t  = threadIdx.x;
    const int nb = blockIdx.x * 16;

    #pragma unroll
    for (int i = 0; i < 2; ++i) {
        int idx = t + i * 256;
        int n   = idx >> 5;
        int c4  = idx & 31;
        int gn  = nb + n; if (gn > N_NODES - 1) gn = N_NODES - 1;
        f32x4 v = *reinterpret_cast<const f32x4*>(x + (size_t)gn * F + c4 * 4);
        *reinterpret_cast<f32x4*>(&xs[n][c4 * 4]) = v;
    }
    __syncthreads();

    const int f  = t & 127;
    const int ng = t >> 7;
    float acc[8] = {0.f, 0.f, 0.f, 0.f, 0.f, 0.f, 0.f, 0.f};

    for (int c4 = 0; c4 < 32; ++c4) {
        float w0 = W1[(4 * c4 + 0) * F + f];
        float w1 = W1[(4 * c4 + 1) * F + f];
        float w2 = W1[(4 * c4 + 2) * F + f];
        float w3 = W1[(4 * c4 + 3) * F + f];
        #pragma unroll
        for (int i = 0; i < 8; ++i) {
            f32x4 xv = *reinterpret_cast<const f32x4*>(&xs[ng * 8 + i][c4 * 4]);
            acc[i] = fmaf(xv.x, w0, fmaf(xv.y, w1, fmaf(xv.z, w2, fmaf(xv.w, w3, acc[i]))));
        }
    }

    #pragma unroll
    for (int i = 0; i < 8; ++i) ts[ng * 8 + i][f] = f2bf(acc[i]);
    __syncthreads();

    {
        const int col = t >> 1, half = t & 1;
        s16x8 v8;
        #pragma unroll
        for (int i = 0; i < 8; ++i) {
            int n = half * 8 + i;
            v8[i] = (nb + n < N_NODES) ? (short)ts[n][col] : (short)0;
        }
        const int kc = nb >> 5, khalf = (nb >> 4) & 1;
        size_t off = (size_t)kc * 4096 + (size_t)(col >> 4) * 512
                   + (size_t)(col & 15) * 32 + khalf * 16 + half * 8;
        *reinterpret_cast<s16x8*>(xwt + off) = v8;
    }
}

// ---------------------------------------------------------------------------
// Kernel 2: partial GEMM, split-K. grid (79 mblocks x 8 splits) x 512 thr.
// Block: 128r x 128c x BK=128. 8 waves = 2m x 2n x 2k; each wave 64x64x64
// (acc 4x4 frags -> 0.5KB LDS-read/MFMA, half of R9). A: 512B-per-row loads,
// f32->bf16 reg-staged into XOR-swizzled LDS; B: linear global_load_lds from
// tiled xwt. Double-buffered, 1 barrier/tile (tile budget ~6400cy >> latency).
// kw-pair reduction in LDS epilogue -> P stays 8-split.
// ---------------------------------------------------------------------------
#define GLOAD(gsrc, ldst) __builtin_amdgcn_global_load_lds(                      \
    (const __attribute__((address_space(1))) unsigned int*)(gsrc),               \
    (__attribute__((address_space(3))) unsigned int*)(ldst), 16, 0, 0)

#define MFMA_(a, b, c) __builtin_amdgcn_mfma_f32_16x16x32_bf16(a, b, c, 0, 0, 0)

__global__ __launch_bounds__(512, 2) void k_gcn(const float* __restrict__ A,
                                                const unsigned short* __restrict__ xwt,
                                                float* __restrict__ P) {
    __shared__ __align__(16) unsigned char Bs[2][32768];   // 64 KB
    __shared__ __align__(16) unsigned char As[2][32768];   // 64 KB
    float (*red)[F] = reinterpret_cast<float (*)[F]>(&Bs[0][0]);  // epilogue overlay

    const int t    = threadIdx.x;
    const int w    = t >> 6;
    const int lane = t & 63;
    const int l16  = lane & 15;
    const int g    = lane >> 4;
    const int mw   = w >> 2;         // 0..1 : 64-row half
    const int nw   = (w >> 1) & 1;   // 0..1 : 64-col half
    const int kw   = w & 1;          // 0..1 : 64-k half of tile
    const int mb    = blockIdx.x % MBLK;
    const int split = blockIdx.x / MBLK;
    const int rbase = mb * BM;

    // ---- A staging: thread t -> row (t>>2), 128B chunk (t&3) of 512B/row ----
    const int srow = t >> 2, c4 = t & 3;
    int arow = rbase + srow; if (arow > N_NODES - 1) arow = N_NODES - 1;
    const size_t aflat = (size_t)arow * N_NODES + (size_t)split * KSPLIT + c4 * 32;
    const size_t alim  = (size_t)N_NODES * N_NODES - 32;

    const unsigned char* const xb = reinterpret_cast<const unsigned char*>(xwt);

    // ---- fragment read byte offsets ----
    int aoff[4][2];   // [mf][kf]: row*256 + (unit ^ (row&7))*16, unit = kw*8+kf*4+g
    #pragma unroll
    for (int mf = 0; mf < 4; ++mf) {
        int row = mw * 64 + mf * 16 + l16;
        #pragma unroll
        for (int kf = 0; kf < 2; ++kf)
            aoff[mf][kf] = row * 256 + ((kw * 8 + kf * 4 + g) ^ (row & 7)) * 16;
    }
    int boff[4][2];   // [nf][kf]: subtile (kc=kw*2+kf, ct=nw*4+nf) + lane part
    #pragma unroll
    for (int nf = 0; nf < 4; ++nf)
        #pragma unroll
        for (int kf = 0; kf < 2; ++kf)
            boff[nf][kf] = ((kw * 2 + kf) * 8 + nw * 4 + nf) * 1024 + l16 * 64 + g * 16;

    f32x4 acc[4][4];
    #pragma unroll
    for (int mf = 0; mf < 4; ++mf)
        #pragma unroll
        for (int nf = 0; nf < 4; ++nf)
            acc[mf][nf] = (f32x4){0.f, 0.f, 0.f, 0.f};

    f32x4 la0, la1, la2, la3, la4, la5, la6, la7;   // 512B/row A stage (128B/thread)

#define LOADA(tile) do {                                                         \
    size_t _fo = aflat + (size_t)(tile) * BK;                                    \
    if (_fo > alim) _fo = alim;                                                  \
    const f32x4* _p = reinterpret_cast<const f32x4*>(A + _fo);                   \
    la0 = _p[0]; la1 = _p[1]; la2 = _p[2]; la3 = _p[3];                          \
    la4 = _p[4]; la5 = _p[5]; la6 = _p[6]; la7 = _p[7];                          \
} while (0)

#define WRITEA(bufA) do {                                                        \
    unsigned char* _r = (bufA) + srow * 256;                                     \
    *reinterpret_cast<bf16x8*>(_r + (((c4*4+0) ^ (srow&7)) * 16)) = pack8(la0, la1); \
    *reinterpret_cast<bf16x8*>(_r + (((c4*4+1) ^ (srow&7)) * 16)) = pack8(la2, la3); \
    *reinterpret_cast<bf16x8*>(_r + (((c4*4+2) ^ (srow&7)) * 16)) = pack8(la4, la5); \
    *reinterpret_cast<bf16x8*>(_r + (((c4*4+3) ^ (srow&7)) * 16)) = pack8(la6, la7); \
} while (0)

#define STAGEB(tile, bufB) do {                                                  \
    const unsigned char* _s = xb + (size_t)(split * 40 + 4 * (tile)) * 8192;     \
    GLOAD(_s + (w * 4 + 0) * 1024 + lane * 16, (bufB) + (w * 4 + 0) * 1024);     \
    GLOAD(_s + (w * 4 + 1) * 1024 + lane * 16, (bufB) + (w * 4 + 1) * 1024);     \
    GLOAD(_s + (w * 4 + 2) * 1024 + lane * 16, (bufB) + (w * 4 + 2) * 1024);     \
    GLOAD(_s + (w * 4 + 3) * 1024 + lane * 16, (bufB) + (w * 4 + 3) * 1024);     \
} while (0)

#define COMPUTE(bufA, bufB) do {                                                 \
    _Pragma("unroll")                                                            \
    for (int kf = 0; kf < 2; ++kf) {                                             \
        bf16x8 af[4], bf[4];                                                     \
        _Pragma("unroll")                                                        \
        for (int i = 0; i < 4; ++i) {                                            \
            af[i] = *reinterpret_cast<const bf16x8*>((bufA) + aoff[i][kf]);      \
            bf[i] = *reinterpret_cast<const bf16x8*>((bufB) + boff[i][kf]);      \
        }                                                                        \
        _Pragma("unroll")                                                        \
        for (int mf = 0; mf < 4; ++mf)                                           \
            _Pragma("unroll")                                                    \
            for (int nf = 0; nf < 4; ++nf)                                       \
                acc[mf][nf] = MFMA_(af[mf], bf[nf], acc[mf][nf]);                \
    }                                                                            \
} while (0)

    // prologue: tile 0 fully staged
    LOADA(0);
    STAGEB(0, &Bs[0][0]);
    WRITEA(&As[0][0]);
    __syncthreads();

    for (int tl = 0; tl < TPS; ++tl) {
        const int cur = tl & 1, nx = cur ^ 1;
        if (tl + 1 < TPS) { LOADA(tl + 1); STAGEB(tl + 1, &Bs[nx][0]); }
        COMPUTE(&As[cur][0], &Bs[cur][0]);
        if (tl + 1 < TPS) WRITEA(&As[nx][0]);
        __syncthreads();
    }

    // ---- epilogue: kw-pair reduction in LDS, then P store (8-split) ----
    // C/D layout (m89): col = lane&15, row = (lane>>4)*4 + reg
    if (kw == 1) {
        #pragma unroll
        for (int mf = 0; mf < 4; ++mf)
            #pragma unroll
            for (int nf = 0; nf < 4; ++nf)
                #pragma unroll
                for (int e = 0; e < 4; ++e)
                    red[mw * 64 + mf * 16 + g * 4 + e][nw * 64 + nf * 16 + l16] = acc[mf][nf][e];
    }
    __syncthreads();
    if (kw == 0) {
        float* Pp = P + ((size_t)split * PROWS + rbase) * F;
        #pragma unroll
        for (int mf = 0; mf < 4; ++mf)
            #pragma unroll
            for (int nf = 0; nf < 4; ++nf)
                #pragma unroll
                for (int e = 0; e < 4; ++e) {
                    int r = mw * 64 + mf * 16 + g * 4 + e;
                    int c = nw * 64 + nf * 16 + l16;
                    Pp[(size_t)r * F + c] = acc[mf][nf][e] + red[r][c];
                }
    }
#undef LOADA
#undef WRITEA
#undef STAGEB
#undef COMPUTE
}

// ---------------------------------------------------------------------------
// Kernel 3: out[r] = relu(sum_s P[s][r][:] + b1) . W2 + b2. grid 5000 x 256.
// ---------------------------------------------------------------------------
__global__ __launch_bounds__(256) void k_red(const float* __restrict__ P,
                                             const float* __restrict__ b1,
                                             const float* __restrict__ W2,
                                             const float* __restrict__ b2,
                                             float* __restrict__ out) {
    __shared__ float sred[4];
    const int t   = threadIdx.x;
    const int row = blockIdx.x * 2 + (t >> 7);
    const int c   = t & 127;

    float v = 0.f;
    #pragma unroll
    for (int s = 0; s < SPLITS; ++s)
        v += P[((size_t)s * PROWS + row) * F + c];
    v = fmaxf(v + b1[c], 0.f) * W2[c];

    v += __shfl_xor(v, 1);
    v += __shfl_xor(v, 2);
    v += __shfl_xor(v, 4);
    v += __shfl_xor(v, 8);
    v += __shfl_xor(v, 16);
    v += __shfl_xor(v, 32);
    if ((t & 63) == 0) sred[t >> 6] = v;
    __syncthreads();
    if (t < 2) out[blockIdx.x * 2 + t] = sred[t * 2] + sred[t * 2 + 1] + b2[0];
}

extern "C" void kernel_launch(void* const* d_in, const int* in_sizes, int n_in,
                              void* d_out, int out_size, void* d_ws, size_t ws_size,
                              hipStream_t stream) {
    const float* x  = (const float*)d_in[0];
    const float* a  = (const float*)d_in[1];
    const float* W1 = (const float*)d_in[2];
    const float* b1 = (const float*)d_in[3];
    const float* W2 = (const float*)d_in[4];
    const float* b2 = (const float*)d_in[5];
    float* out = (float*)d_out;

    unsigned short* xwt = (unsigned short*)d_ws;                  // 2.62 MB tiled
    float* P = (float*)((char*)d_ws + (size_t)(32 << 20));        // 8x10112x128 f32

    k_xw<<<640, 256, 0, stream>>>(x, W1, xwt);
    k_gcn<<<MBLK * SPLITS, 512, 0, stream>>>(a, xwt, P);
    k_red<<<5000, 256, 0, stream>>>(P, b1, W2, b2, out);
}